// Round 12
// baseline (324.798 us; speedup 1.0000x reference)
//
#include <hip/hip_runtime.h>

// ---------------------------------------------------------------------------
// Problem: h = relu(x + noise); BN1d(train, eps=0.8); z = hn @ W^T + b
// Folded form: z = h @ (scale*W)^T + (b + W @ shift),  h = relu(x+noise)
// x: [8192, 4096] f32, W: [4096, 4096] f32, out: [8192, 4096] f32
// R8 baseline 292 us (GEMM 231 @ 16x16 MFMA). This round: 32x32x16 MFMA
// (15-20% better pipe rate, m119), same LDS layout / T2 swizzle / R7 ledger.
// ---------------------------------------------------------------------------

#define B_ROWS 8192
#define C_CH   4096
#define N_OUT  4096

// ---------------------- compile-time noise table --------------------------
struct alignas(16) NoiseTable { float v[C_CH]; };

constexpr NoiseTable make_noise() {
    unsigned s = 123u;
    unsigned pool[C_CH] = {};
    for (int i = 0; i < C_CH; ++i) { s = 65539u * s + 1u; pool[i] = s; }
    int nxt = C_CH - 1;
    NoiseTable t{};
    for (int i = 0; i < C_CH; ++i) {
        nxt = (int)(pool[nxt] % (unsigned)C_CH);
        t.v[i] = (float)((double)pool[nxt] * 1e-9);
        s = 65539u * s + 1u;
        pool[nxt] = s;
    }
    return t;
}

__device__ constexpr NoiseTable NOISE = make_noise();

// ---------------------- helpers -------------------------------------------
__device__ __forceinline__ unsigned short f2bf(float f) {
    unsigned u = __builtin_bit_cast(unsigned, f);
    unsigned r = (u + 0x7FFFu + ((u >> 16) & 1u)) >> 16;   // RNE
    return (unsigned short)r;
}

typedef __attribute__((ext_vector_type(8)))  short bf16x8;
typedef __attribute__((ext_vector_type(4)))  float f32x4;
typedef __attribute__((ext_vector_type(16))) float f32x16;

__device__ __forceinline__ void gload16(const void* g, void* l) {
    __builtin_amdgcn_global_load_lds(
        (const __attribute__((address_space(1))) void*)g,
        (__attribute__((address_space(3))) void*)l, 16, 0, 0);
}

#define BARRIER()  do { __builtin_amdgcn_s_barrier(); asm volatile("" ::: "memory"); } while (0)
#define SCHED0()   __builtin_amdgcn_sched_barrier(0)
#define LGKM(N)    do { asm volatile("s_waitcnt lgkmcnt(" #N ")" ::: "memory"); \
                        __builtin_amdgcn_sched_barrier(0); } while (0)

// ------- 1) fused: h = relu(x+noise) -> bf16, + per-block BN partials -------
__global__ __launch_bounds__(256) void conv_h_kernel(const float* __restrict__ x,
                                                     unsigned short* __restrict__ Hbf,
                                                     float* __restrict__ psum,
                                                     float* __restrict__ psumsq) {
    const int t = threadIdx.x;
    const int b = blockIdx.x;

    float4 nv[4];
    #pragma unroll
    for (int g = 0; g < 4; ++g)
        nv[g] = *reinterpret_cast<const float4*>(&NOISE.v[g * 1024 + 4 * t]);

    float4 s[4], q[4];
    #pragma unroll
    for (int g = 0; g < 4; ++g) { s[g] = make_float4(0,0,0,0); q[g] = make_float4(0,0,0,0); }

    const int row0 = b * 16;
    for (int r = 0; r < 16; ++r) {
        const size_t rb = (size_t)(row0 + r) * C_CH;
        const float* xr = x + rb;
        #pragma unroll
        for (int g = 0; g < 4; ++g) {
            float4 v = *reinterpret_cast<const float4*>(&xr[g * 1024 + 4 * t]);
            float h0 = fmaxf(v.x + nv[g].x, 0.f);
            float h1 = fmaxf(v.y + nv[g].y, 0.f);
            float h2 = fmaxf(v.z + nv[g].z, 0.f);
            float h3 = fmaxf(v.w + nv[g].w, 0.f);
            s[g].x += h0; s[g].y += h1; s[g].z += h2; s[g].w += h3;
            q[g].x += h0*h0; q[g].y += h1*h1; q[g].z += h2*h2; q[g].w += h3*h3;
            ushort4 o;
            o.x = f2bf(h0); o.y = f2bf(h1); o.z = f2bf(h2); o.w = f2bf(h3);
            *reinterpret_cast<ushort4*>(&Hbf[rb + g * 1024 + 4 * t]) = o;
        }
    }
    #pragma unroll
    for (int g = 0; g < 4; ++g) {
        *reinterpret_cast<float4*>(&psum  [(size_t)b * C_CH + g * 1024 + 4 * t]) = s[g];
        *reinterpret_cast<float4*>(&psumsq[(size_t)b * C_CH + g * 1024 + 4 * t]) = q[g];
    }
}

// ------- 2) finalize (parallel): scale/shift per channel -------------------
__global__ __launch_bounds__(256) void finalize_kernel(const float* __restrict__ psum,
                                                       const float* __restrict__ psumsq,
                                                       const float* __restrict__ gamma,
                                                       const float* __restrict__ beta,
                                                       float* __restrict__ scale,
                                                       float* __restrict__ shift) {
    __shared__ float ls[8][32], lq[8][32];
    const int t  = threadIdx.x;
    const int c  = blockIdx.x * 32 + (t & 31);
    const int g  = t >> 5;
    float s = 0.f, q = 0.f;
    const int bk0 = g * 64;
    for (int bk = bk0; bk < bk0 + 64; ++bk) {
        s += psum  [(size_t)bk * C_CH + c];
        q += psumsq[(size_t)bk * C_CH + c];
    }
    ls[g][t & 31] = s; lq[g][t & 31] = q;
    __syncthreads();
    if (t < 32) {
        float S = 0.f, Q = 0.f;
        #pragma unroll
        for (int g2 = 0; g2 < 8; ++g2) { S += ls[g2][t]; Q += lq[g2][t]; }
        const int ch = blockIdx.x * 32 + t;
        const float inv  = 1.f / (float)B_ROWS;
        const float mean = S * inv;
        const float var  = fmaxf(Q * inv - mean * mean, 0.f);
        const float sc   = gamma[ch] / sqrtf(var + 0.8f);
        scale[ch] = sc;
        shift[ch] = beta[ch] - mean * sc;
    }
}

// ------- 3) convW': W' = scale*W (bf16) + bias' = b + W @ shift (f32) -------
__global__ __launch_bounds__(256) void convW_kernel(const float* __restrict__ W,
                                                    const float* __restrict__ scale,
                                                    const float* __restrict__ shift,
                                                    const float* __restrict__ b,
                                                    unsigned short* __restrict__ Wbf,
                                                    float* __restrict__ biasN) {
    const int wv   = threadIdx.x >> 6;
    const int lane = threadIdx.x & 63;
    const int o    = blockIdx.x * 4 + wv;
    const float* wr = W + (size_t)o * C_CH;
    unsigned short* wo = Wbf + (size_t)o * C_CH;

    float acc = 0.f;
    #pragma unroll
    for (int s = 0; s < 16; ++s) {
        const int c = s * 256 + lane * 4;
        float4 v  = *reinterpret_cast<const float4*>(&wr[c]);
        float4 sc = *reinterpret_cast<const float4*>(&scale[c]);
        float4 sh = *reinterpret_cast<const float4*>(&shift[c]);
        ushort4 ov;
        ov.x = f2bf(v.x * sc.x); ov.y = f2bf(v.y * sc.y);
        ov.z = f2bf(v.z * sc.z); ov.w = f2bf(v.w * sc.w);
        *reinterpret_cast<ushort4*>(&wo[c]) = ov;
        acc += sh.x * v.x + sh.y * v.y + sh.z * v.z + sh.w * v.w;
    }
    #pragma unroll
    for (int off = 32; off > 0; off >>= 1)
        acc += __shfl_down(acc, off);
    if (lane == 0) biasN[o] = b[o] + acc;
}

// ---------------------- 4) GEMM 256x256x64, 32x32x16 MFMA ------------------
// LDS layout / staging / T2 swizzle / ledger identical to R7-best:
// buffer 65536 B, A chunks A0..A3 (64 rows x 64 k) at 0/8192/16384/24576,
// B chunks at +32768; stage order ph0 {B0,B1}, ph1 {B2,B3}, ph2 {A0,A2},
// ph3 {A1,A3}; waits vmcnt(2)@barrier1, vmcnt(4)@barrier2; counted lgkmcnt.
//
// NEW: mfma_f32_32x32x16_bf16 (m119: 2495 TF pipe ceiling vs 2176 for 16x16).
// Per wave: 4 mi-frags (32 rows) x 2 ni-frags (32 cols) x 4 K-steps = 32 MFMA.
// Fragment read: lane l -> row l&31, k-group (l>>5); logical 16B-slot
// s = ks*2 + (l>>5); phys slot = s ^ (row&7) (row&7 == l&7). Consecutive
// 8-lane groups hit 8 distinct slots -> conflict-free.
// First half reads chunks {A(2wm), B(wn)} (certified @barrier1); second half
// {A(2wm+1)} (certified @barrier2) — same need structure as R7.

template<bool STG>
__device__ __forceinline__ void tile_step(
    char* lds, const int bc, const int bn,
    const char*& pA0, const char*& pA1, const char*& pA2, const char*& pA3,
    const char*& pB0, const char*& pB1, const char*& pB2, const char*& pB3,
    const int dstw, const int arow, const int brow, const int (&xoff)[4],
    f32x16 (&acc)[4][2]) {

    bf16x8 af[2][4], bfr[2][4];

    // ======== first half: mi0-1 x ni0-1 ========
    asm volatile("s_waitcnt vmcnt(2)" ::: "memory");   // B0-3,A0,A2 of t landed
    BARRIER();                        // block-wide landing + bn reuse fence
    SCHED0();
    if (STG) {
        gload16(pB0, lds + bn + 32768 + dstw);
        gload16(pB1, lds + bn + 40960 + dstw);
    }
    // group 1 (12 reads): af mi0-1 all ks + bfr ni0 all ks
    #pragma unroll
    for (int mi = 0; mi < 2; ++mi)
        #pragma unroll
        for (int ks = 0; ks < 4; ++ks)
            af[mi][ks] = *reinterpret_cast<const bf16x8*>(lds + bc + arow + mi * 4096 + xoff[ks]);
    #pragma unroll
    for (int ks = 0; ks < 4; ++ks)
        bfr[0][ks] = *reinterpret_cast<const bf16x8*>(lds + bc + brow + xoff[ks]);
    SCHED0();
    // group 2 (4 reads): bfr ni1
    #pragma unroll
    for (int ks = 0; ks < 4; ++ks)
        bfr[1][ks] = *reinterpret_cast<const bf16x8*>(lds + bc + brow + 4096 + xoff[ks]);
    LGKM(4);                          // group 1 done; group 2 drains under Q00
    __builtin_amdgcn_s_setprio(1);
    #pragma unroll
    for (int ks = 0; ks < 4; ++ks)
        #pragma unroll
        for (int mi = 0; mi < 2; ++mi)
            acc[mi][0] = __builtin_amdgcn_mfma_f32_32x32x16_bf16(
                af[mi][ks], bfr[0][ks], acc[mi][0], 0, 0, 0);
    __builtin_amdgcn_s_setprio(0);
    if (STG) {
        gload16(pB2, lds + bn + 49152 + dstw);
        gload16(pB3, lds + bn + 57344 + dstw);
    }
    LGKM(0);                          // group 2 done
    __builtin_amdgcn_s_setprio(1);
    #pragma unroll
    for (int ks = 0; ks < 4; ++ks)
        #pragma unroll
        for (int mi = 0; mi < 2; ++mi)
            acc[mi][1] = __builtin_amdgcn_mfma_f32_32x32x16_bf16(
                af[mi][ks], bfr[1][ks], acc[mi][1], 0, 0, 0);
    __builtin_amdgcn_s_setprio(0);

    // ======== second half: mi2-3 x ni0-1 ========
    if (STG) asm volatile("s_waitcnt vmcnt(4)" ::: "memory");  // A1,A3 of t landed
    else     asm volatile("s_waitcnt vmcnt(0)" ::: "memory");
    BARRIER();
    SCHED0();
    if (STG) {
        gload16(pA0, lds + bn +     0 + dstw);
        gload16(pA2, lds + bn + 16384 + dstw);
    }
    // group 3 (4 reads): af mi2
    #pragma unroll
    for (int ks = 0; ks < 4; ++ks)
        af[0][ks] = *reinterpret_cast<const bf16x8*>(lds + bc + arow + 2 * 4096 + xoff[ks]);
    SCHED0();
    // group 4 (4 reads): af mi3
    #pragma unroll
    for (int ks = 0; ks < 4; ++ks)
        af[1][ks] = *reinterpret_cast<const bf16x8*>(lds + bc + arow + 3 * 4096 + xoff[ks]);
    LGKM(4);                          // group 3 done; group 4 drains under MFMA
    __builtin_amdgcn_s_setprio(1);
    #pragma unroll
    for (int ks = 0; ks < 4; ++ks)
        acc[2][1] = __builtin_amdgcn_mfma_f32_32x32x16_bf16(
            af[0][ks], bfr[1][ks], acc[2][1], 0, 0, 0);
    __builtin_amdgcn_s_setprio(0);
    if (STG) {
        gload16(pA1, lds + bn +  8192 + dstw);
        gload16(pA3, lds + bn + 24576 + dstw);
        pA0 += 128; pA1 += 128; pA2 += 128; pA3 += 128;
        pB0 += 128; pB1 += 128; pB2 += 128; pB3 += 128;
    }
    LGKM(0);                          // group 4 done
    __builtin_amdgcn_s_setprio(1);
    #pragma unroll
    for (int ks = 0; ks < 4; ++ks)
        acc[3][1] = __builtin_amdgcn_mfma_f32_32x32x16_bf16(
            af[1][ks], bfr[1][ks], acc[3][1], 0, 0, 0);
    #pragma unroll
    for (int ks = 0; ks < 4; ++ks)
        #pragma unroll
        for (int mi = 0; mi < 2; ++mi)
            acc[2 + mi][0] = __builtin_amdgcn_mfma_f32_32x32x16_bf16(
                af[mi][ks], bfr[0][ks], acc[2 + mi][0], 0, 0, 0);
    __builtin_amdgcn_s_setprio(0);
}

__global__ __launch_bounds__(512, 2) void gemm256_kernel(
    const unsigned short* __restrict__ A, const unsigned short* __restrict__ B,
    const float* __restrict__ bias, float* __restrict__ C) {
    constexpr int K = C_CH, N = N_OUT;
    __shared__ alignas(128) char lds[131072];

    // XCD-bijective swizzle (nwg = 512, % 8 == 0)
    const int nwg = gridDim.x;
    const int cpx = nwg >> 3;
    int wg = blockIdx.x;
    wg = (wg & 7) * cpx + (wg >> 3);
    const int nbx = N >> 8;                 // 16
    const int bx = wg % nbx, by = wg / nbx;
    const int row0 = by << 8, col0 = bx << 8;

    const int t    = threadIdx.x;
    const int lane = t & 63;
    const int wid  = t >> 6;
    const int wm   = wid >> 2;              // 0..1
    const int wn   = wid & 3;               // 0..3
    const int l31  = lane & 31;
    const int lk   = lane >> 5;             // 0..1 (k-group)
    const int x7   = lane & 7;

    // staging source (pre-swizzled slot) and wave-uniform LDS dest
    const int sslot = (lane & 7) ^ (lane >> 3);
    const int dstw  = wid << 10;            // wid * 1024

    const char* pA0 = (const char*)A +
        ((size_t)(row0 + wid * 8 + (lane >> 3)) * K) * 2 + sslot * 16;
    const char* pA1 = pA0 + 1 * 64 * K * 2;
    const char* pA2 = pA0 + 2 * 64 * K * 2;
    const char* pA3 = pA0 + 3 * 64 * K * 2;
    const char* pB0 = (const char*)B +
        ((size_t)(col0 + wid * 8 + (lane >> 3)) * K) * 2 + sslot * 16;
    const char* pB1 = pB0 + 1 * 64 * K * 2;
    const char* pB2 = pB0 + 2 * 64 * K * 2;
    const char* pB3 = pB0 + 3 * 64 * K * 2;

    // fragment read geometry (T2 swizzle: slot ^ (row&7), row&7 == lane&7)
    int xoff[4];
    #pragma unroll
    for (int ks = 0; ks < 4; ++ks)
        xoff[ks] = (((ks * 2 + lk) ^ x7) << 4);
    const int arow = wm * 16384 + l31 * 128;            // A base (+ mi*4096)
    const int brow = 32768 + wn * 8192 + l31 * 128;     // B base (+ ni*4096)

    f32x16 acc[4][2];
    #pragma unroll
    for (int mi = 0; mi < 4; ++mi)
        #pragma unroll
        for (int ni = 0; ni < 2; ++ni)
            acc[mi][ni] = (f32x16)(0.f);

    // prologue: stage tile 0 into buf0 in vmcnt-matched order
    // (B0,B1,B2,B3,A0,A2 = oldest 6; A1,A3 = newest 2)
    gload16(pB0, lds + 32768 + dstw);
    gload16(pB1, lds + 40960 + dstw);
    gload16(pB2, lds + 49152 + dstw);
    gload16(pB3, lds + 57344 + dstw);
    gload16(pA0, lds +     0 + dstw);
    gload16(pA2, lds + 16384 + dstw);
    gload16(pA1, lds +  8192 + dstw);
    gload16(pA3, lds + 24576 + dstw);
    pA0 += 128; pA1 += 128; pA2 += 128; pA3 += 128;
    pB0 += 128; pB1 += 128; pB2 += 128; pB3 += 128;

    // 64 K-tiles: 31 double iterations + staged tile + tail tile
    #pragma unroll 1
    for (int it = 0; it < 31; ++it) {
        tile_step<true >(lds,     0, 65536, pA0, pA1, pA2, pA3, pB0, pB1, pB2, pB3,
                         dstw, arow, brow, xoff, acc);
        tile_step<true >(lds, 65536,     0, pA0, pA1, pA2, pA3, pB0, pB1, pB2, pB3,
                         dstw, arow, brow, xoff, acc);
    }
    tile_step<true >(lds,     0, 65536, pA0, pA1, pA2, pA3, pB0, pB1, pB2, pB3,
                     dstw, arow, brow, xoff, acc);
    tile_step<false>(lds, 65536,     0, pA0, pA1, pA2, pA3, pB0, pB1, pB2, pB3,
                     dstw, arow, brow, xoff, acc);

    // epilogue: C/D map (m74/m101): col = lane&31, row = (r&3)+8*(r>>2)+4*lk
    const int crow0 = row0 + wm * 128 + 4 * lk;
    const int ccol0 = col0 + wn * 64 + l31;
    #pragma unroll
    for (int ni = 0; ni < 2; ++ni) {
        const float bv = bias[ccol0 + ni * 32];
        #pragma unroll
        for (int mi = 0; mi < 4; ++mi) {
            #pragma unroll
            for (int r4 = 0; r4 < 4; ++r4) {
                const size_t base = (size_t)(crow0 + mi * 32 + r4 * 8) * N + (ccol0 + ni * 32);
                #pragma unroll
                for (int j = 0; j < 4; ++j)
                    C[base + (size_t)j * N] = acc[mi][ni][r4 * 4 + j] + bv;
            }
        }
    }
}

// ---------------------- launch --------------------------------------------
extern "C" void kernel_launch(void* const* d_in, const int* in_sizes, int n_in,
                              void* d_out, int out_size, void* d_ws, size_t ws_size,
                              hipStream_t stream) {
    const float* x     = (const float*)d_in[0];
    const float* gamma = (const float*)d_in[1];
    const float* beta  = (const float*)d_in[2];
    const float* W     = (const float*)d_in[3];
    const float* b     = (const float*)d_in[4];
    float* out = (float*)d_out;

    char* ws = (char*)d_ws;
    unsigned short* Hbf = (unsigned short*)(ws);                       // 64 MiB
    unsigned short* Wbf = (unsigned short*)(ws + 67108864);            // 32 MiB
    float* psum   = (float*)(ws + 100663296);                          // 8 MiB
    float* psumsq = (float*)(ws + 109051904);                          // 8 MiB
    float* scale  = (float*)(ws + 117440512);                          // 16 KiB
    float* shift  = (float*)(ws + 117440512 + 16384);                  // 16 KiB
    float* biasN  = (float*)(ws + 117440512 + 32768);                  // 16 KiB

    hipLaunchKernelGGL(conv_h_kernel,   dim3(512),  dim3(256), 0, stream,
                       x, Hbf, psum, psumsq);
    hipLaunchKernelGGL(finalize_kernel, dim3(128),  dim3(256), 0, stream,
                       psum, psumsq, gamma, beta, scale, shift);
    hipLaunchKernelGGL(convW_kernel,    dim3(1024), dim3(256), 0, stream,
                       W, scale, shift, b, Wbf, biasN);
    hipLaunchKernelGGL(gemm256_kernel,  dim3(512),  dim3(512), 0, stream,
                       Hbf, Wbf, biasN, out);
}

// Round 13
// 290.932 us; speedup vs baseline: 1.1164x; 1.1164x over previous
//
#include <hip/hip_runtime.h>

// ---------------------------------------------------------------------------
// Problem: h = relu(x + noise); BN1d(train, eps=0.8); z = hn @ W^T + b
// Folded form: z = h @ (scale*W)^T + (b + W @ shift),  h = relu(x+noise)
// x: [8192, 4096] f32, W: [4096, 4096] f32, out: [8192, 4096] f32
// FINAL (R8 config, measured 292.0 us): conv_h 512 blk, finalize 128 blk,
// convW 1024 blk, GEMM 256x256x64 R7 schedule (231 us @ MfmaUtil ~52).
// Closed experiments: R4 deep-flight -6%, R5 8-barrier -5%, R9 4-slot -6%,
// R10 single-sync -11%, R12 32x32-MFMA -13% (4-way LDS conflict, 2.5e7).
// ---------------------------------------------------------------------------

#define B_ROWS 8192
#define C_CH   4096
#define N_OUT  4096

// ---------------------- compile-time noise table --------------------------
struct alignas(16) NoiseTable { float v[C_CH]; };

constexpr NoiseTable make_noise() {
    unsigned s = 123u;
    unsigned pool[C_CH] = {};
    for (int i = 0; i < C_CH; ++i) { s = 65539u * s + 1u; pool[i] = s; }
    int nxt = C_CH - 1;
    NoiseTable t{};
    for (int i = 0; i < C_CH; ++i) {
        nxt = (int)(pool[nxt] % (unsigned)C_CH);
        t.v[i] = (float)((double)pool[nxt] * 1e-9);
        s = 65539u * s + 1u;
        pool[nxt] = s;
    }
    return t;
}

__device__ constexpr NoiseTable NOISE = make_noise();

// ---------------------- helpers -------------------------------------------
__device__ __forceinline__ unsigned short f2bf(float f) {
    unsigned u = __builtin_bit_cast(unsigned, f);
    unsigned r = (u + 0x7FFFu + ((u >> 16) & 1u)) >> 16;   // RNE
    return (unsigned short)r;
}

typedef __attribute__((ext_vector_type(8))) short bf16x8;
typedef __attribute__((ext_vector_type(4))) float f32x4;

__device__ __forceinline__ void gload16(const void* g, void* l) {
    __builtin_amdgcn_global_load_lds(
        (const __attribute__((address_space(1))) void*)g,
        (__attribute__((address_space(3))) void*)l, 16, 0, 0);
}

#define BARRIER()  do { __builtin_amdgcn_s_barrier(); asm volatile("" ::: "memory"); } while (0)
#define SCHED0()   __builtin_amdgcn_sched_barrier(0)
#define LGKM(N)    do { asm volatile("s_waitcnt lgkmcnt(" #N ")" ::: "memory"); \
                        __builtin_amdgcn_sched_barrier(0); } while (0)

// ------- 1) fused: h = relu(x+noise) -> bf16, + per-block BN partials -------
__global__ __launch_bounds__(256) void conv_h_kernel(const float* __restrict__ x,
                                                     unsigned short* __restrict__ Hbf,
                                                     float* __restrict__ psum,
                                                     float* __restrict__ psumsq) {
    const int t = threadIdx.x;
    const int b = blockIdx.x;

    float4 nv[4];
    #pragma unroll
    for (int g = 0; g < 4; ++g)
        nv[g] = *reinterpret_cast<const float4*>(&NOISE.v[g * 1024 + 4 * t]);

    float4 s[4], q[4];
    #pragma unroll
    for (int g = 0; g < 4; ++g) { s[g] = make_float4(0,0,0,0); q[g] = make_float4(0,0,0,0); }

    const int row0 = b * 16;
    for (int r = 0; r < 16; ++r) {
        const size_t rb = (size_t)(row0 + r) * C_CH;
        const float* xr = x + rb;
        #pragma unroll
        for (int g = 0; g < 4; ++g) {
            float4 v = *reinterpret_cast<const float4*>(&xr[g * 1024 + 4 * t]);
            float h0 = fmaxf(v.x + nv[g].x, 0.f);
            float h1 = fmaxf(v.y + nv[g].y, 0.f);
            float h2 = fmaxf(v.z + nv[g].z, 0.f);
            float h3 = fmaxf(v.w + nv[g].w, 0.f);
            s[g].x += h0; s[g].y += h1; s[g].z += h2; s[g].w += h3;
            q[g].x += h0*h0; q[g].y += h1*h1; q[g].z += h2*h2; q[g].w += h3*h3;
            ushort4 o;
            o.x = f2bf(h0); o.y = f2bf(h1); o.z = f2bf(h2); o.w = f2bf(h3);
            *reinterpret_cast<ushort4*>(&Hbf[rb + g * 1024 + 4 * t]) = o;
        }
    }
    #pragma unroll
    for (int g = 0; g < 4; ++g) {
        *reinterpret_cast<float4*>(&psum  [(size_t)b * C_CH + g * 1024 + 4 * t]) = s[g];
        *reinterpret_cast<float4*>(&psumsq[(size_t)b * C_CH + g * 1024 + 4 * t]) = q[g];
    }
}

// ------- 2) finalize (parallel): scale/shift per channel -------------------
// 128 blocks x 32 channels. Thread t: channel bid*32+(t&31), partial-group
// t>>5 (64 of the 512 partial rows); LDS 8x32 tree reduce. Deterministic.
__global__ __launch_bounds__(256) void finalize_kernel(const float* __restrict__ psum,
                                                       const float* __restrict__ psumsq,
                                                       const float* __restrict__ gamma,
                                                       const float* __restrict__ beta,
                                                       float* __restrict__ scale,
                                                       float* __restrict__ shift) {
    __shared__ float ls[8][32], lq[8][32];
    const int t  = threadIdx.x;
    const int c  = blockIdx.x * 32 + (t & 31);
    const int g  = t >> 5;
    float s = 0.f, q = 0.f;
    const int bk0 = g * 64;
    for (int bk = bk0; bk < bk0 + 64; ++bk) {
        s += psum  [(size_t)bk * C_CH + c];
        q += psumsq[(size_t)bk * C_CH + c];
    }
    ls[g][t & 31] = s; lq[g][t & 31] = q;
    __syncthreads();
    if (t < 32) {
        float S = 0.f, Q = 0.f;
        #pragma unroll
        for (int g2 = 0; g2 < 8; ++g2) { S += ls[g2][t]; Q += lq[g2][t]; }
        const int ch = blockIdx.x * 32 + t;
        const float inv  = 1.f / (float)B_ROWS;
        const float mean = S * inv;
        const float var  = fmaxf(Q * inv - mean * mean, 0.f);
        const float sc   = gamma[ch] / sqrtf(var + 0.8f);
        scale[ch] = sc;
        shift[ch] = beta[ch] - mean * sc;
    }
}

// ------- 3) convW': W' = scale*W (bf16) + bias' = b + W @ shift (f32) -------
__global__ __launch_bounds__(256) void convW_kernel(const float* __restrict__ W,
                                                    const float* __restrict__ scale,
                                                    const float* __restrict__ shift,
                                                    const float* __restrict__ b,
                                                    unsigned short* __restrict__ Wbf,
                                                    float* __restrict__ biasN) {
    const int wv   = threadIdx.x >> 6;
    const int lane = threadIdx.x & 63;
    const int o    = blockIdx.x * 4 + wv;
    const float* wr = W + (size_t)o * C_CH;
    unsigned short* wo = Wbf + (size_t)o * C_CH;

    float acc = 0.f;
    #pragma unroll
    for (int s = 0; s < 16; ++s) {
        const int c = s * 256 + lane * 4;
        float4 v  = *reinterpret_cast<const float4*>(&wr[c]);
        float4 sc = *reinterpret_cast<const float4*>(&scale[c]);
        float4 sh = *reinterpret_cast<const float4*>(&shift[c]);
        ushort4 ov;
        ov.x = f2bf(v.x * sc.x); ov.y = f2bf(v.y * sc.y);
        ov.z = f2bf(v.z * sc.z); ov.w = f2bf(v.w * sc.w);
        *reinterpret_cast<ushort4*>(&wo[c]) = ov;
        acc += sh.x * v.x + sh.y * v.y + sh.z * v.z + sh.w * v.w;
    }
    #pragma unroll
    for (int off = 32; off > 0; off >>= 1)
        acc += __shfl_down(acc, off);
    if (lane == 0) biasN[o] = b[o] + acc;
}

// ---------------------- 4) GEMM 256x256x64 (R7 schedule, measured best) ----
// LDS buffer 65536 B: A chunks A0..A3 (64 rows each) at 0/8192/16384/24576,
// B chunks at +32768. T2 swizzle slot^(row&7), source pre-swizzled.
// Stage order for t+1: ph0 {B0,B1}, ph1 {B2,B3}, ph2 {A0,A2}, ph3 {A1,A3};
// waits vmcnt(2)@barrier1, vmcnt(4)@barrier2. 2 barriers/K-tile. Fragment
// ds_reads issued in sched_barrier-ordered groups, waited with counted lgkmcnt.
// 16x16x32 MFMA: fragment reads span 16 rows/instr -> 2 lanes/bank (free);
// 32x32 spans 32 rows -> 4-way conflict with 128B rows (R12, measured).

template<int MH, int NH>
__device__ __forceinline__ void quad_mfma(bf16x8 (&af)[4][2], bf16x8 (&bfr)[4][2],
                                          f32x4 (&acc)[8][4]) {
    #pragma unroll
    for (int s = 0; s < 2; ++s)
        #pragma unroll
        for (int m = 0; m < 4; ++m)
            #pragma unroll
            for (int n = 0; n < 2; ++n)
                acc[MH * 4 + m][NH * 2 + n] = __builtin_amdgcn_mfma_f32_16x16x32_bf16(
                    af[m][s], bfr[NH * 2 + n][s], acc[MH * 4 + m][NH * 2 + n], 0, 0, 0);
}

template<bool STG>
__device__ __forceinline__ void tile_step(
    char* lds, const int bc, const int bn,
    const char*& pA0, const char*& pA1, const char*& pA2, const char*& pA3,
    const char*& pB0, const char*& pB1, const char*& pB2, const char*& pB3,
    const int dstw, const int aoff0, const int aoff1,
    const int boff0, const int boff1,
    f32x4 (&acc)[8][4]) {

    bf16x8 af[4][2], bfr[4][2];

    // ======== first half: Q00 + Q01 ========
    asm volatile("s_waitcnt vmcnt(2)" ::: "memory");   // B0-3,A0,A2 of t landed
    BARRIER();                        // block-wide landing + bn reuse fence
    SCHED0();
    if (STG) {
        gload16(pB0, lds + bn + 32768 + dstw);
        gload16(pB1, lds + bn + 40960 + dstw);
    }
    // group 1 (12 reads): af m0-3 both k-slots + bf n0-1
    #pragma unroll
    for (int m = 0; m < 4; ++m) {
        af[m][0] = *reinterpret_cast<const bf16x8*>(lds + bc + aoff0 + m * 2048);
        af[m][1] = *reinterpret_cast<const bf16x8*>(lds + bc + aoff1 + m * 2048);
    }
    #pragma unroll
    for (int n = 0; n < 2; ++n) {
        bfr[n][0] = *reinterpret_cast<const bf16x8*>(lds + bc + boff0 + n * 2048);
        bfr[n][1] = *reinterpret_cast<const bf16x8*>(lds + bc + boff1 + n * 2048);
    }
    SCHED0();
    // group 2 (4 reads): bf n2-3
    #pragma unroll
    for (int n = 2; n < 4; ++n) {
        bfr[n][0] = *reinterpret_cast<const bf16x8*>(lds + bc + boff0 + n * 2048);
        bfr[n][1] = *reinterpret_cast<const bf16x8*>(lds + bc + boff1 + n * 2048);
    }
    LGKM(4);                          // group 1 done; group 2 drains under Q00
    __builtin_amdgcn_s_setprio(1);
    quad_mfma<0, 0>(af, bfr, acc);
    __builtin_amdgcn_s_setprio(0);
    if (STG) {
        gload16(pB2, lds + bn + 49152 + dstw);
        gload16(pB3, lds + bn + 57344 + dstw);
    }
    LGKM(0);                          // group 2 done
    __builtin_amdgcn_s_setprio(1);
    quad_mfma<0, 1>(af, bfr, acc);
    __builtin_amdgcn_s_setprio(0);

    // ======== second half: Q11 + Q10 ========
    if (STG) asm volatile("s_waitcnt vmcnt(4)" ::: "memory");  // A1,A3 of t landed
    else     asm volatile("s_waitcnt vmcnt(0)" ::: "memory");
    BARRIER();
    SCHED0();
    if (STG) {
        gload16(pA0, lds + bn +     0 + dstw);
        gload16(pA2, lds + bn + 16384 + dstw);
    }
    // group 3 (4 reads): af[0..1] <- phys rows m4,m5
    #pragma unroll
    for (int m = 0; m < 2; ++m) {
        af[m][0] = *reinterpret_cast<const bf16x8*>(lds + bc + aoff0 + (m + 4) * 2048);
        af[m][1] = *reinterpret_cast<const bf16x8*>(lds + bc + aoff1 + (m + 4) * 2048);
    }
    SCHED0();
    // group 4 (4 reads): af[2..3] <- phys rows m6,m7
    #pragma unroll
    for (int m = 2; m < 4; ++m) {
        af[m][0] = *reinterpret_cast<const bf16x8*>(lds + bc + aoff0 + (m + 4) * 2048);
        af[m][1] = *reinterpret_cast<const bf16x8*>(lds + bc + aoff1 + (m + 4) * 2048);
    }
    LGKM(4);                          // group 3 done; group 4 drains under MFMA
    __builtin_amdgcn_s_setprio(1);
    #pragma unroll
    for (int s = 0; s < 2; ++s)
        #pragma unroll
        for (int m = 0; m < 2; ++m)
            #pragma unroll
            for (int n = 2; n < 4; ++n)
                acc[4 + m][n] = __builtin_amdgcn_mfma_f32_16x16x32_bf16(
                    af[m][s], bfr[n][s], acc[4 + m][n], 0, 0, 0);
    __builtin_amdgcn_s_setprio(0);
    if (STG) {
        gload16(pA1, lds + bn +  8192 + dstw);
        gload16(pA3, lds + bn + 24576 + dstw);
        pA0 += 128; pA1 += 128; pA2 += 128; pA3 += 128;
        pB0 += 128; pB1 += 128; pB2 += 128; pB3 += 128;
    }
    LGKM(0);                          // group 4 done
    __builtin_amdgcn_s_setprio(1);
    #pragma unroll
    for (int s = 0; s < 2; ++s)
        #pragma unroll
        for (int m = 2; m < 4; ++m)
            #pragma unroll
            for (int n = 2; n < 4; ++n)
                acc[4 + m][n] = __builtin_amdgcn_mfma_f32_16x16x32_bf16(
                    af[m][s], bfr[n][s], acc[4 + m][n], 0, 0, 0);
    // Q10: pure register
    #pragma unroll
    for (int s = 0; s < 2; ++s)
        #pragma unroll
        for (int m = 0; m < 4; ++m)
            #pragma unroll
            for (int n = 0; n < 2; ++n)
                acc[4 + m][n] = __builtin_amdgcn_mfma_f32_16x16x32_bf16(
                    af[m][s], bfr[n][s], acc[4 + m][n], 0, 0, 0);
    __builtin_amdgcn_s_setprio(0);
}

__global__ __launch_bounds__(512, 2) void gemm256_kernel(
    const unsigned short* __restrict__ A, const unsigned short* __restrict__ B,
    const float* __restrict__ bias, float* __restrict__ C) {
    constexpr int K = C_CH, N = N_OUT;
    __shared__ alignas(128) char lds[131072];

    // XCD-bijective swizzle (nwg = 512, % 8 == 0)
    const int nwg = gridDim.x;
    const int cpx = nwg >> 3;
    int wg = blockIdx.x;
    wg = (wg & 7) * cpx + (wg >> 3);
    const int nbx = N >> 8;                 // 16
    const int bx = wg % nbx, by = wg / nbx;
    const int row0 = by << 8, col0 = bx << 8;

    const int t    = threadIdx.x;
    const int lane = t & 63;
    const int wid  = t >> 6;
    const int wm   = wid >> 2;              // 0..1
    const int wn   = wid & 3;               // 0..3
    const int l15  = lane & 15;
    const int lh   = lane >> 4;             // 0..3

    // staging source (pre-swizzled slot) and wave-uniform LDS dest
    const int sslot = (lane & 7) ^ (lane >> 3);
    const int dstw  = wid << 10;            // wid * 1024

    const char* pA0 = (const char*)A +
        ((size_t)(row0 + wid * 8 + (lane >> 3)) * K) * 2 + sslot * 16;
    const char* pA1 = pA0 + 1 * 64 * K * 2;
    const char* pA2 = pA0 + 2 * 64 * K * 2;
    const char* pA3 = pA0 + 3 * 64 * K * 2;
    const char* pB0 = (const char*)B +
        ((size_t)(col0 + wid * 8 + (lane >> 3)) * K) * 2 + sslot * 16;
    const char* pB1 = pB0 + 1 * 64 * K * 2;
    const char* pB2 = pB0 + 2 * 64 * K * 2;
    const char* pB3 = pB0 + 3 * 64 * K * 2;

    // fragment read offsets (T2 swizzle: slot ^ (row&7), row&7 == l15&7)
    const int x7 = l15 & 7;
    const int aoff0 = wm * 16384 + l15 * 128 + ((lh     ) ^ x7) * 16;
    const int aoff1 = wm * 16384 + l15 * 128 + ((lh +  4) ^ x7) * 16;
    const int boff0 = 32768 + wn * 8192 + l15 * 128 + ((lh    ) ^ x7) * 16;
    const int boff1 = 32768 + wn * 8192 + l15 * 128 + ((lh + 4) ^ x7) * 16;

    f32x4 acc[8][4];
    #pragma unroll
    for (int m = 0; m < 8; ++m)
        #pragma unroll
        for (int n = 0; n < 4; ++n)
            acc[m][n] = (f32x4){0.f, 0.f, 0.f, 0.f};

    // prologue: stage tile 0 into buf0 in vmcnt-matched order
    // (B0,B1,B2,B3,A0,A2 = oldest 6; A1,A3 = newest 2)
    gload16(pB0, lds + 32768 + dstw);
    gload16(pB1, lds + 40960 + dstw);
    gload16(pB2, lds + 49152 + dstw);
    gload16(pB3, lds + 57344 + dstw);
    gload16(pA0, lds +     0 + dstw);
    gload16(pA2, lds + 16384 + dstw);
    gload16(pA1, lds +  8192 + dstw);
    gload16(pA3, lds + 24576 + dstw);
    pA0 += 128; pA1 += 128; pA2 += 128; pA3 += 128;
    pB0 += 128; pB1 += 128; pB2 += 128; pB3 += 128;

    // 64 K-tiles: 31 double iterations + staged tile + tail tile
    #pragma unroll 1
    for (int it = 0; it < 31; ++it) {
        tile_step<true >(lds,     0, 65536, pA0, pA1, pA2, pA3, pB0, pB1, pB2, pB3,
                         dstw, aoff0, aoff1, boff0, boff1, acc);
        tile_step<true >(lds, 65536,     0, pA0, pA1, pA2, pA3, pB0, pB1, pB2, pB3,
                         dstw, aoff0, aoff1, boff0, boff1, acc);
    }
    tile_step<true >(lds,     0, 65536, pA0, pA1, pA2, pA3, pB0, pB1, pB2, pB3,
                     dstw, aoff0, aoff1, boff0, boff1, acc);
    tile_step<false>(lds, 65536,     0, pA0, pA1, pA2, pA3, pB0, pB1, pB2, pB3,
                     dstw, aoff0, aoff1, boff0, boff1, acc);

    // epilogue: C[row][col] = acc + bias[col]
    const int crow0 = row0 + wm * 128 + lh * 4;
    const int ccol0 = col0 + wn * 64 + l15;
    #pragma unroll
    for (int n = 0; n < 4; ++n) {
        const float bv = bias[ccol0 + n * 16];
        #pragma unroll
        for (int m = 0; m < 8; ++m) {
            const size_t base = (size_t)(crow0 + m * 16) * N + (ccol0 + n * 16);
            #pragma unroll
            for (int j = 0; j < 4; ++j)
                C[base + (size_t)j * N] = acc[m][n][j] + bv;
        }
    }
}

// ---------------------- launch --------------------------------------------
extern "C" void kernel_launch(void* const* d_in, const int* in_sizes, int n_in,
                              void* d_out, int out_size, void* d_ws, size_t ws_size,
                              hipStream_t stream) {
    const float* x     = (const float*)d_in[0];
    const float* gamma = (const float*)d_in[1];
    const float* beta  = (const float*)d_in[2];
    const float* W     = (const float*)d_in[3];
    const float* b     = (const float*)d_in[4];
    float* out = (float*)d_out;

    char* ws = (char*)d_ws;
    unsigned short* Hbf = (unsigned short*)(ws);                       // 64 MiB
    unsigned short* Wbf = (unsigned short*)(ws + 67108864);            // 32 MiB
    float* psum   = (float*)(ws + 100663296);                          // 8 MiB
    float* psumsq = (float*)(ws + 109051904);                          // 8 MiB
    float* scale  = (float*)(ws + 117440512);                          // 16 KiB
    float* shift  = (float*)(ws + 117440512 + 16384);                  // 16 KiB
    float* biasN  = (float*)(ws + 117440512 + 32768);                  // 16 KiB

    hipLaunchKernelGGL(conv_h_kernel,   dim3(512),  dim3(256), 0, stream,
                       x, Hbf, psum, psumsq);
    hipLaunchKernelGGL(finalize_kernel, dim3(128),  dim3(256), 0, stream,
                       psum, psumsq, gamma, beta, scale, shift);
    hipLaunchKernelGGL(convW_kernel,    dim3(1024), dim3(256), 0, stream,
                       W, scale, shift, b, Wbf, biasN);
    hipLaunchKernelGGL(gemm256_kernel,  dim3(512),  dim3(512), 0, stream,
                       Hbf, Wbf, biasN, out);
}